// Round 6
// baseline (1572.003 us; speedup 1.0000x reference)
//
#include <hip/hip_runtime.h>

// ---------------------------------------------------------------------------
// SuperpixelEbli, CV=32. Branches SEQUENTIAL, one buffer set (peak ~160.6 MB;
// ~161.5 MB proven backed). CSR build = deterministic radix partition into a
// SELF-CONTAINED, ROW-SORTED edge stream cv[p] = {rl<<19|col, val}:
//   kphist/kpscan1/kbscan/kpscatter as r4 (no global atomics).
//   kplace: row-sorts each bucket AND persists per-row degrees rcnt[] (u8,
//           max deg ~40) so layers never re-derive row boundaries.
// LAYER = ONE FUSED KERNEL kfused (r5) = spmm + bias + readout + next-proj:
//   1 WG per TWO 128-row buckets (256 rows). r6: phase1 (32MB cv re-read +
//   4M LDS atomics + scan per layer -> the 1.77M bank conflicts in r5's
//   counters) replaced by a 256B rcnt load + LDS scan. cv loads are
//   NONTEMPORAL (no L3 allocate) so Infinity Cache is dedicated to the
//   randomly-gathered 64MB Z table (r5 FETCH showed ~50% Z L3-hit only).
//   Phase2: thread t = row t, sequential 8B/edge payload + Z[col] gather
//   (2 full lines), REGISTER acc[32]. Epilogue row-local: h=acc+b; readout
//   r=h@Wl_slice -> LDS per-graph partials -> S atomics; if l<2:
//   Zout = leaky(h)@Wnext^T (Z/ZB ping-pong; H array eliminated in r5).
//   History: r2 916MB fetch (cols/vals indirection); r3 LDS-atomic spmm
//   LDS-pipe-bound @690us; r4 register-acc @155us; r5 fused @168us.
// Then classifier + softmax.
// ---------------------------------------------------------------------------

namespace {
constexpr int kG = 512;
constexpr int kNmax = 524288;
constexpr int kEmax = 4194304;
constexpr int kNCH = 256;  // partition chunks (blocks)

// workspace layout (bytes); peak ~160.6 MB
constexpr size_t OFF_TOT = 0;                                // 4096 int (bucket totals)
constexpr size_t OFF_BB  = OFF_TOT + 16384;                  // 4097 int (bucket bases)
constexpr size_t OFF_CV  = 32768;                            // kEmax int2 = 32 MB
constexpr size_t OFF_Z   = OFF_CV + (size_t)kEmax * 8;       // kNmax*32 f32 (cnts overlay in build)
constexpr size_t OFF_ZB  = OFF_Z + (size_t)kNmax * 128;      // kNmax*32 f32 (tmp overlay in build)
constexpr size_t OFF_S   = OFF_ZB + (size_t)kNmax * 128;     // 3*512*10 f32
constexpr size_t OFF_CNT = OFF_S + (size_t)3 * kG * 10 * 4;  // 3*512 f32
constexpr size_t OFF_RC  = OFF_CNT + (size_t)3 * kG * 4;     // kNmax u8 (row degrees)
}  // namespace

__device__ __forceinline__ void atomAddF(float* p, float v) {
  __hip_atomic_fetch_add(p, v, __ATOMIC_RELAXED, __HIP_MEMORY_SCOPE_AGENT);
}

// ---------------- radix partition (no global atomics) ----------------

// per-block LDS histogram over NB = n/128 buckets; cnts[b][k] contiguous.
__global__ void kphist(const int* __restrict__ rows, int* __restrict__ cnts,
                       int NB, int chunk) {
  __shared__ int cnt[4096];
  int t = threadIdx.x, b = blockIdx.x;
  for (int k = t; k < NB; k += 256) cnt[k] = 0;
  __syncthreads();
  int base = b * chunk;
  for (int i = t; i < chunk; i += 256) atomicAdd(&cnt[rows[base + i] >> 7], 1);
  __syncthreads();
  for (int k = t; k < NB; k += 256) cnts[(size_t)b * NB + k] = cnt[k];
}

// per-bucket exclusive scan over the kNCH blocks (1 WG per bucket);
// also emits the bucket total.
__global__ void kpscan1(int* __restrict__ cnts, int* __restrict__ tot, int NB) {
  __shared__ int sA[256], sB[256];
  int k = blockIdx.x, t = threadIdx.x;
  int v = cnts[(size_t)t * NB + k];
  sA[t] = v;
  __syncthreads();
  int* src = sA;
  int* dst = sB;
  for (int off = 1; off < 256; off <<= 1) {
    int x = src[t];
    if (t >= off) x += src[t - off];
    dst[t] = x;
    __syncthreads();
    int* tm = src; src = dst; dst = tm;
  }
  cnts[(size_t)t * NB + k] = src[t] - v;  // exclusive over blocks
  if (t == 255) tot[k] = src[255];        // bucket total
}

// single block: exclusive scan of tot[0..NB) -> bbase[0..NB], bbase[NB]=E.
__global__ void kbscan(const int* __restrict__ tot, int* __restrict__ bbase,
                       int NB, int E) {
  __shared__ int sA[1024], sB[1024];
  int t = threadIdx.x;
  int C = NB >> 10;  // 1, 2 or 4
  int loc[4];
  int s = 0;
  for (int i = 0; i < C; i++) { loc[i] = tot[t * C + i]; s += loc[i]; }
  sA[t] = s;
  __syncthreads();
  int* src = sA;
  int* dst = sB;
  for (int off = 1; off < 1024; off <<= 1) {
    int x = src[t];
    if (t >= off) x += src[t - off];
    dst[t] = x;
    __syncthreads();
    int* tm = src; src = dst; dst = tm;
  }
  int excl = src[t] - s;
  for (int i = 0; i < C; i++) { bbase[t * C + i] = excl; excl += loc[i]; }
  if (t == 0) bbase[NB] = E;
}

// scatter edges to bucket-major tmp = {rl<<19 | col, val} using LDS cursors
// seeded from bbase[k] + per-block prefix. rows/cols/vals read sequentially.
__global__ void kpscatter(const int* __restrict__ rows, const int* __restrict__ cols,
                          const float* __restrict__ vals, const int* __restrict__ cnts,
                          const int* __restrict__ bbase, int2* __restrict__ tmp,
                          int NB, int chunk) {
  __shared__ int cur[4096];
  int t = threadIdx.x, b = blockIdx.x;
  for (int k = t; k < NB; k += 256)
    cur[k] = bbase[k] + cnts[(size_t)b * NB + k];
  __syncthreads();
  int base = b * chunk;
  for (int i = t; i < chunk; i += 256) {
    int e = base + i;
    int r = rows[e];
    int c = cols[e];
    float v = vals[e];
    int p = atomicAdd(&cur[r >> 7], 1);
    tmp[p] = make_int2(((r & 127) << 19) | c, __float_as_int(v));
  }
}

// row-sort each bucket: LDS hist(rl) + scan -> per-row cursors; rewrite the
// bucket's edges into cv at row-sorted positions (8KB window, L2-local).
// Also persists per-row degrees rcnt[] (u8) for the fused layers.
__global__ void kplace(const int2* __restrict__ tmp, const int* __restrict__ bbase,
                       int2* __restrict__ cv, unsigned char* __restrict__ rcnt) {
  __shared__ int sA[256], sB[256];
  __shared__ int lcur[128];
  int k = blockIdx.x, t = threadIdx.x;
  int s = bbase[k], e = bbase[k + 1];
  sA[t] = 0;
  __syncthreads();
  for (int p = s + t; p < e; p += 256) atomicAdd(&sA[tmp[p].x >> 19], 1);
  __syncthreads();
  int v = sA[t];
  if (t < 128) rcnt[(k << 7) + t] = (unsigned char)v;
  int* src = sA;
  int* dst = sB;
  for (int off = 1; off < 256; off <<= 1) {
    int x = src[t];
    if (t >= off) x += src[t - off];
    dst[t] = x;
    __syncthreads();
    int* tm = src; src = dst; dst = tm;
  }
  if (t < 128) lcur[t] = s + src[t] - v;  // exclusive start of row t
  __syncthreads();
  for (int p = s + t; p < e; p += 256) {
    int2 pk = tmp[p];
    int pos = atomicAdd(&lcur[pk.x >> 19], 1);
    cv[pos] = pk;
  }
}

// ---------------- dense passes ----------------

// Z = X @ W^T   (X: n x 32, W: 32 x 32), no bias
__global__ void kproj(const float* __restrict__ X, const float* __restrict__ W,
                      float* __restrict__ Z) {
  __shared__ float w[1024];
  for (int k = threadIdx.x; k < 1024; k += 256) w[k] = W[k];
  __syncthreads();
  int i = blockIdx.x * 256 + threadIdx.x;
  float x[32];
  const float4* xp = (const float4*)(X + (size_t)i * 32);
#pragma unroll
  for (int q = 0; q < 8; q++) {
    float4 t = xp[q];
    x[4 * q] = t.x; x[4 * q + 1] = t.y; x[4 * q + 2] = t.z; x[4 * q + 3] = t.w;
  }
  float z[32];
#pragma unroll
  for (int o = 0; o < 32; o++) {
    float a = 0.f;
#pragma unroll
    for (int f = 0; f < 32; f++) a += w[o * 32 + f] * x[f];
    z[o] = a;
  }
  float4* zr = (float4*)(Z + (size_t)i * 32);
#pragma unroll
  for (int q = 0; q < 8; q++)
    zr[q] = make_float4(z[4 * q], z[4 * q + 1], z[4 * q + 2], z[4 * q + 3]);
}

// ---------------- fused layer: SpMM + bias + readout + next-proj ----------
// 1 WG per TWO 128-row buckets (256 rows, 256 threads).
// Row bounds from rcnt (u8 degrees) + LDS scan (no cv re-read).
// Phase2: register-acc SpMM, cv loads nontemporal (keep L3 for Z).
// Epilogue: h = acc+b; r = h@Wl_slice -> per-graph LDS partials -> S;
// if !dolast: Zout[row] = leaky(h)@Wnext^T.
__global__ void kfused(const int2* __restrict__ cv, const int* __restrict__ bbase,
                       const unsigned char* __restrict__ rcnt,
                       const float* __restrict__ Zin, float* __restrict__ Zout,
                       const float* __restrict__ b, const float* __restrict__ Wl,
                       int l, const float* __restrict__ Wnext,
                       const int* __restrict__ batch, float* __restrict__ S,
                       float* __restrict__ cnt, int docnt, int dolast) {
  __shared__ int sA[256], sB[256];
  __shared__ float wl[320];   // wl[o*32+j] = Wl[o][32l+j]
  __shared__ float w2[1024];  // Wnext (row-major 32x32)
  __shared__ float bb[32];
  __shared__ float part[8][10];
  __shared__ int pcnt[8];
  __shared__ int g0s;
  int k2 = blockIdx.x, t = threadIdx.x;

  for (int k = t; k < 320; k += 256) wl[k] = Wl[(k / 32) * 96 + 32 * l + (k % 32)];
  if (!dolast)
    for (int k = t; k < 1024; k += 256) w2[k] = Wnext[k];
  if (t < 32) bb[t] = b[t];
  if (t < 80) part[t / 10][t % 10] = 0.f;
  if (t < 8) pcnt[t] = 0;
  if (t == 0) g0s = batch[k2 * 256];

  // row boundaries: per-row degree + LDS scan (rows k2*256 .. k2*256+255)
  int s = bbase[2 * k2];
  int v = (int)rcnt[k2 * 256 + t];
  sA[t] = v;
  __syncthreads();
  int* src = sA;
  int* dst = sB;
  for (int off = 1; off < 256; off <<= 1) {
    int x = src[t];
    if (t >= off) x += src[t - off];
    dst[t] = x;
    __syncthreads();
    int* tm = src; src = dst; dst = tm;
  }
  int p1 = s + src[t];  // start of next row
  int p0 = p1 - v;      // start of this row

  // phase 2: register-accumulated gather; cv via nontemporal 8B loads
  float acc[32];
#pragma unroll
  for (int j = 0; j < 32; j++) acc[j] = 0.f;
  const long long* cvl = (const long long*)cv;
  for (int p = p0; p < p1; p++) {
    long long pk = __builtin_nontemporal_load(&cvl[p]);
    int key = (int)pk;
    int col = key & 0x7FFFF;
    float vv = __int_as_float((int)(pk >> 32));
    const float4* zr = (const float4*)(Zin + (size_t)col * 32);
#pragma unroll
    for (int q = 0; q < 8; q++) {
      float4 z = zr[q];
      acc[4 * q + 0] += vv * z.x; acc[4 * q + 1] += vv * z.y;
      acc[4 * q + 2] += vv * z.z; acc[4 * q + 3] += vv * z.w;
    }
  }

  // epilogue: bias, readout, per-graph partials
#pragma unroll
  for (int j = 0; j < 32; j++) acc[j] += bb[j];
  float r[10];
#pragma unroll
  for (int o = 0; o < 10; o++) {
    float a = 0.f;
#pragma unroll
    for (int j = 0; j < 32; j++) a += wl[o * 32 + j] * acc[j];
    r[o] = a;
  }
  int g0 = g0s;
  int g = batch[k2 * 256 + t];
  int gl = g - g0;
  if (gl >= 0 && gl < 8) {
#pragma unroll
    for (int o = 0; o < 10; o++) atomicAdd(&part[gl][o], r[o]);
    if (docnt) atomicAdd(&pcnt[gl], 1);
  } else {
#pragma unroll
    for (int o = 0; o < 10; o++) atomAddF(&S[(size_t)g * 10 + o], r[o]);
    if (docnt) atomAddF(&cnt[g], 1.f);
  }

  // next-layer projection: Zout = leaky(h) @ Wnext^T
  if (!dolast) {
#pragma unroll
    for (int j = 0; j < 32; j++) acc[j] = (acc[j] >= 0.f) ? acc[j] : 0.01f * acc[j];
    float z[32];
#pragma unroll
    for (int o = 0; o < 32; o++) {
      float a = 0.f;
#pragma unroll
      for (int f = 0; f < 32; f++) a += w2[o * 32 + f] * acc[f];
      z[o] = a;
    }
    int row = k2 * 256 + t;
    float4* zr = (float4*)(Zout + (size_t)row * 32);
#pragma unroll
    for (int q = 0; q < 8; q++)
      zr[q] = make_float4(z[4 * q], z[4 * q + 1], z[4 * q + 2], z[4 * q + 3]);
  }

  // flush per-graph partials
  __syncthreads();
  if (t < 80) {
    int gl2 = t / 10, o = t % 10;
    int gg = g0 + gl2;
    float pv = part[gl2][o];
    if (gg < kG && pv != 0.f) atomAddF(&S[(size_t)gg * 10 + o], pv);
  }
  if (docnt && t < 8) {
    int gg = g0 + t;
    if (gg < kG && pcnt[t] > 0) atomAddF(&cnt[gg], (float)pcnt[t]);
  }
}

// out = softmax(concat(S_b / max(cnt_b,1)) @ Wc^T + bc)   Wc: (10,30)
__global__ void kfinal(const float* __restrict__ S, const float* __restrict__ cnt,
                       const float* __restrict__ Wc, const float* __restrict__ bc,
                       float* __restrict__ out) {
  int g = threadIdx.x;  // 512 threads, one per graph
  float o[30];
#pragma unroll
  for (int s = 0; s < 3; s++) {
    float c = cnt[s * kG + g];
    float inv = 1.f / fmaxf(c, 1.f);
#pragma unroll
    for (int j = 0; j < 10; j++)
      o[s * 10 + j] = S[((size_t)s * kG + g) * 10 + j] * inv;
  }
  float z[10];
  float m = -1e30f;
#pragma unroll
  for (int k = 0; k < 10; k++) {
    float t = bc[k];
    for (int j = 0; j < 30; j++) t += Wc[k * 30 + j] * o[j];
    z[k] = t;
    m = fmaxf(m, t);
  }
  float sum = 0.f;
#pragma unroll
  for (int k = 0; k < 10; k++) { z[k] = expf(z[k] - m); sum += z[k]; }
  float r = 1.f / sum;
#pragma unroll
  for (int k = 0; k < 10; k++) out[(size_t)g * 10 + k] = z[k] * r;
}

extern "C" void kernel_launch(void* const* d_in, const int* in_sizes, int n_in,
                              void* d_out, int out_size, void* d_ws, size_t ws_size,
                              hipStream_t stream) {
  const int nb[3] = {262144, 524288, 131072};
  const int eb[3] = {2097152, 4194304, 1048576};

  const int* rowsv[3] = {(const int*)d_in[0], (const int*)d_in[5], (const int*)d_in[10]};
  const int* colsv[3] = {(const int*)d_in[1], (const int*)d_in[6], (const int*)d_in[11]};
  const float* valsv[3] = {(const float*)d_in[2], (const float*)d_in[7], (const float*)d_in[12]};
  const float* Xv[3] = {(const float*)d_in[3], (const float*)d_in[8], (const float*)d_in[13]};
  const int* batchv[3] = {(const int*)d_in[4], (const int*)d_in[9], (const int*)d_in[14]};
  // per-branch weights: W1,b1,W2,b2,W3,b3,Wl,bl at [15..22], [23..30], [31..38]
  const float* W1v[3] = {(const float*)d_in[15], (const float*)d_in[23], (const float*)d_in[31]};
  const float* B1v[3] = {(const float*)d_in[16], (const float*)d_in[24], (const float*)d_in[32]};
  const float* W2v[3] = {(const float*)d_in[17], (const float*)d_in[25], (const float*)d_in[33]};
  const float* B2v[3] = {(const float*)d_in[18], (const float*)d_in[26], (const float*)d_in[34]};
  const float* W3v[3] = {(const float*)d_in[19], (const float*)d_in[27], (const float*)d_in[35]};
  const float* B3v[3] = {(const float*)d_in[20], (const float*)d_in[28], (const float*)d_in[36]};
  const float* Wlv[3] = {(const float*)d_in[21], (const float*)d_in[29], (const float*)d_in[37]};
  const float* Wc = (const float*)d_in[39];
  const float* bc = (const float*)d_in[40];

  char* ws = (char*)d_ws;
  int* tot = (int*)(ws + OFF_TOT);
  int* bbase = (int*)(ws + OFF_BB);
  int2* cv = (int2*)(ws + OFF_CV);
  float* Z = (float*)(ws + OFF_Z);
  float* ZB = (float*)(ws + OFF_ZB);
  float* S = (float*)(ws + OFF_S);
  float* cnt = (float*)(ws + OFF_CNT);
  unsigned char* rcnt = (unsigned char*)(ws + OFF_RC);
  float* out = (float*)d_out;

  hipMemsetAsync(S, 0, (size_t)3 * kG * 10 * 4 + (size_t)3 * kG * 4, stream);

  for (int b = 0; b < 3; b++) {
    const int n = nb[b], e = eb[b];
    const int NB = n / 128;       // radix buckets (<=4096)
    const int chunk = e / kNCH;   // edges per partition block
    const float* Bl[3] = {B1v[b], B2v[b], B3v[b]};
    float* Sb = S + (size_t)b * kG * 10;
    float* cb = cnt + (size_t)b * kG;
    int* cnts = (int*)(ws + OFF_Z);   // Z region idle during build (4MB)
    int2* tmp = (int2*)(ws + OFF_ZB); // ZB region idle during build (32MB)

    // deterministic partition into self-contained, row-sorted cv stream
    kphist<<<kNCH, 256, 0, stream>>>(rowsv[b], cnts, NB, chunk);
    kpscan1<<<NB, 256, 0, stream>>>(cnts, tot, NB);
    kbscan<<<1, 1024, 0, stream>>>(tot, bbase, NB, e);
    kpscatter<<<kNCH, 256, 0, stream>>>(rowsv[b], colsv[b], valsv[b], cnts,
                                        bbase, tmp, NB, chunk);
    kplace<<<NB, 256, 0, stream>>>(tmp, bbase, cv, rcnt);

    // layer 1 projection (overwrites cnts overlay; build is complete)
    kproj<<<n / 256, 256, 0, stream>>>(Xv[b], W1v[b], Z);

    // 3 fused layers: Z -> ZB -> Z -> (readout only)
    kfused<<<NB / 2, 256, 0, stream>>>(cv, bbase, rcnt, Z, ZB, Bl[0], Wlv[b], 0,
                                       W2v[b], batchv[b], Sb, cb, 1, 0);
    kfused<<<NB / 2, 256, 0, stream>>>(cv, bbase, rcnt, ZB, Z, Bl[1], Wlv[b], 1,
                                       W3v[b], batchv[b], Sb, cb, 0, 0);
    kfused<<<NB / 2, 256, 0, stream>>>(cv, bbase, rcnt, Z, nullptr, Bl[2], Wlv[b], 2,
                                       W2v[b] /*unused*/, batchv[b], Sb, cb, 0, 1);
  }

  kfinal<<<1, 512, 0, stream>>>(S, cnt, Wc, bc, out);
}

// Round 7
// 1423.615 us; speedup vs baseline: 1.1042x; 1.1042x over previous
//
#include <hip/hip_runtime.h>

// ---------------------------------------------------------------------------
// SuperpixelEbli, CV=32. Branches SEQUENTIAL, one buffer set (peak ~160.6 MB;
// ~161.5 MB proven backed). CSR build = deterministic radix partition into a
// SELF-CONTAINED, ROW-SORTED edge stream cv[p] = {rl<<19|col, val}:
//   kphist/kpscan1/kbscan/kpscatter as r4 (no global atomics).
//   kplace: row-sorts each bucket AND persists per-row degrees rcnt[] (u8,
//           max deg ~40) so layers never re-derive row boundaries.
// LAYER = ONE FUSED KERNEL kfused = spmm + bias + readout + next-proj:
//   1 WG per TWO 128-row buckets (256 rows). Row bounds from rcnt (256B) +
//   LDS scan -- r6 replaced the per-layer 32MB cv histogram re-read (was
//   1.77M bank conflicts). cv loads are PLAIN loads: r6's nontemporal hint
//   killed intra-thread line reuse (8 seq 8B payloads share a 64B line) and
//   cost +120MB FETCH / +29us -- reverted in r7.
//   Phase2: thread t = row t, sequential 8B/edge payload + Z[col] gather
//   (2 full lines), REGISTER acc[32]. Epilogue row-local: h=acc+b; readout
//   r=h@Wl_slice -> LDS per-graph partials -> S atomics; if l<2:
//   Zout = leaky(h)@Wnext^T (Z/ZB ping-pong; H array eliminated in r5).
//   History: r2 916MB fetch (cols/vals indirection); r3 LDS-atomic spmm
//   LDS-pipe-bound @690us; r4 register-acc @155us; r5 fused @168us;
//   r6 rcnt win + nt loss @197us.
// Then classifier + softmax.
// ---------------------------------------------------------------------------

namespace {
constexpr int kG = 512;
constexpr int kNmax = 524288;
constexpr int kEmax = 4194304;
constexpr int kNCH = 256;  // partition chunks (blocks)

// workspace layout (bytes); peak ~160.6 MB
constexpr size_t OFF_TOT = 0;                                // 4096 int (bucket totals)
constexpr size_t OFF_BB  = OFF_TOT + 16384;                  // 4097 int (bucket bases)
constexpr size_t OFF_CV  = 32768;                            // kEmax int2 = 32 MB
constexpr size_t OFF_Z   = OFF_CV + (size_t)kEmax * 8;       // kNmax*32 f32 (cnts overlay in build)
constexpr size_t OFF_ZB  = OFF_Z + (size_t)kNmax * 128;      // kNmax*32 f32 (tmp overlay in build)
constexpr size_t OFF_S   = OFF_ZB + (size_t)kNmax * 128;     // 3*512*10 f32
constexpr size_t OFF_CNT = OFF_S + (size_t)3 * kG * 10 * 4;  // 3*512 f32
constexpr size_t OFF_RC  = OFF_CNT + (size_t)3 * kG * 4;     // kNmax u8 (row degrees)
}  // namespace

__device__ __forceinline__ void atomAddF(float* p, float v) {
  __hip_atomic_fetch_add(p, v, __ATOMIC_RELAXED, __HIP_MEMORY_SCOPE_AGENT);
}

// ---------------- radix partition (no global atomics) ----------------

// per-block LDS histogram over NB = n/128 buckets; cnts[b][k] contiguous.
__global__ void kphist(const int* __restrict__ rows, int* __restrict__ cnts,
                       int NB, int chunk) {
  __shared__ int cnt[4096];
  int t = threadIdx.x, b = blockIdx.x;
  for (int k = t; k < NB; k += 256) cnt[k] = 0;
  __syncthreads();
  int base = b * chunk;
  for (int i = t; i < chunk; i += 256) atomicAdd(&cnt[rows[base + i] >> 7], 1);
  __syncthreads();
  for (int k = t; k < NB; k += 256) cnts[(size_t)b * NB + k] = cnt[k];
}

// per-bucket exclusive scan over the kNCH blocks (1 WG per bucket);
// also emits the bucket total.
__global__ void kpscan1(int* __restrict__ cnts, int* __restrict__ tot, int NB) {
  __shared__ int sA[256], sB[256];
  int k = blockIdx.x, t = threadIdx.x;
  int v = cnts[(size_t)t * NB + k];
  sA[t] = v;
  __syncthreads();
  int* src = sA;
  int* dst = sB;
  for (int off = 1; off < 256; off <<= 1) {
    int x = src[t];
    if (t >= off) x += src[t - off];
    dst[t] = x;
    __syncthreads();
    int* tm = src; src = dst; dst = tm;
  }
  cnts[(size_t)t * NB + k] = src[t] - v;  // exclusive over blocks
  if (t == 255) tot[k] = src[255];        // bucket total
}

// single block: exclusive scan of tot[0..NB) -> bbase[0..NB], bbase[NB]=E.
__global__ void kbscan(const int* __restrict__ tot, int* __restrict__ bbase,
                       int NB, int E) {
  __shared__ int sA[1024], sB[1024];
  int t = threadIdx.x;
  int C = NB >> 10;  // 1, 2 or 4
  int loc[4];
  int s = 0;
  for (int i = 0; i < C; i++) { loc[i] = tot[t * C + i]; s += loc[i]; }
  sA[t] = s;
  __syncthreads();
  int* src = sA;
  int* dst = sB;
  for (int off = 1; off < 1024; off <<= 1) {
    int x = src[t];
    if (t >= off) x += src[t - off];
    dst[t] = x;
    __syncthreads();
    int* tm = src; src = dst; dst = tm;
  }
  int excl = src[t] - s;
  for (int i = 0; i < C; i++) { bbase[t * C + i] = excl; excl += loc[i]; }
  if (t == 0) bbase[NB] = E;
}

// scatter edges to bucket-major tmp = {rl<<19 | col, val} using LDS cursors
// seeded from bbase[k] + per-block prefix. rows/cols/vals read sequentially.
__global__ void kpscatter(const int* __restrict__ rows, const int* __restrict__ cols,
                          const float* __restrict__ vals, const int* __restrict__ cnts,
                          const int* __restrict__ bbase, int2* __restrict__ tmp,
                          int NB, int chunk) {
  __shared__ int cur[4096];
  int t = threadIdx.x, b = blockIdx.x;
  for (int k = t; k < NB; k += 256)
    cur[k] = bbase[k] + cnts[(size_t)b * NB + k];
  __syncthreads();
  int base = b * chunk;
  for (int i = t; i < chunk; i += 256) {
    int e = base + i;
    int r = rows[e];
    int c = cols[e];
    float v = vals[e];
    int p = atomicAdd(&cur[r >> 7], 1);
    tmp[p] = make_int2(((r & 127) << 19) | c, __float_as_int(v));
  }
}

// row-sort each bucket: LDS hist(rl) + scan -> per-row cursors; rewrite the
// bucket's edges into cv at row-sorted positions (8KB window, L2-local).
// Also persists per-row degrees rcnt[] (u8) for the fused layers.
__global__ void kplace(const int2* __restrict__ tmp, const int* __restrict__ bbase,
                       int2* __restrict__ cv, unsigned char* __restrict__ rcnt) {
  __shared__ int sA[256], sB[256];
  __shared__ int lcur[128];
  int k = blockIdx.x, t = threadIdx.x;
  int s = bbase[k], e = bbase[k + 1];
  sA[t] = 0;
  __syncthreads();
  for (int p = s + t; p < e; p += 256) atomicAdd(&sA[tmp[p].x >> 19], 1);
  __syncthreads();
  int v = sA[t];
  if (t < 128) rcnt[(k << 7) + t] = (unsigned char)v;
  int* src = sA;
  int* dst = sB;
  for (int off = 1; off < 256; off <<= 1) {
    int x = src[t];
    if (t >= off) x += src[t - off];
    dst[t] = x;
    __syncthreads();
    int* tm = src; src = dst; dst = tm;
  }
  if (t < 128) lcur[t] = s + src[t] - v;  // exclusive start of row t
  __syncthreads();
  for (int p = s + t; p < e; p += 256) {
    int2 pk = tmp[p];
    int pos = atomicAdd(&lcur[pk.x >> 19], 1);
    cv[pos] = pk;
  }
}

// ---------------- dense passes ----------------

// Z = X @ W^T   (X: n x 32, W: 32 x 32), no bias
__global__ void kproj(const float* __restrict__ X, const float* __restrict__ W,
                      float* __restrict__ Z) {
  __shared__ float w[1024];
  for (int k = threadIdx.x; k < 1024; k += 256) w[k] = W[k];
  __syncthreads();
  int i = blockIdx.x * 256 + threadIdx.x;
  float x[32];
  const float4* xp = (const float4*)(X + (size_t)i * 32);
#pragma unroll
  for (int q = 0; q < 8; q++) {
    float4 t = xp[q];
    x[4 * q] = t.x; x[4 * q + 1] = t.y; x[4 * q + 2] = t.z; x[4 * q + 3] = t.w;
  }
  float z[32];
#pragma unroll
  for (int o = 0; o < 32; o++) {
    float a = 0.f;
#pragma unroll
    for (int f = 0; f < 32; f++) a += w[o * 32 + f] * x[f];
    z[o] = a;
  }
  float4* zr = (float4*)(Z + (size_t)i * 32);
#pragma unroll
  for (int q = 0; q < 8; q++)
    zr[q] = make_float4(z[4 * q], z[4 * q + 1], z[4 * q + 2], z[4 * q + 3]);
}

// ---------------- fused layer: SpMM + bias + readout + next-proj ----------
// 1 WG per TWO 128-row buckets (256 rows, 256 threads).
// Row bounds from rcnt (u8 degrees) + LDS scan (no cv re-read).
// Phase2: register-acc SpMM, plain cv loads (intra-thread line reuse).
// Epilogue: h = acc+b; r = h@Wl_slice -> per-graph LDS partials -> S;
// if !dolast: Zout[row] = leaky(h)@Wnext^T.
__global__ void kfused(const int2* __restrict__ cv, const int* __restrict__ bbase,
                       const unsigned char* __restrict__ rcnt,
                       const float* __restrict__ Zin, float* __restrict__ Zout,
                       const float* __restrict__ b, const float* __restrict__ Wl,
                       int l, const float* __restrict__ Wnext,
                       const int* __restrict__ batch, float* __restrict__ S,
                       float* __restrict__ cnt, int docnt, int dolast) {
  __shared__ int sA[256], sB[256];
  __shared__ float wl[320];   // wl[o*32+j] = Wl[o][32l+j]
  __shared__ float w2[1024];  // Wnext (row-major 32x32)
  __shared__ float bb[32];
  __shared__ float part[8][10];
  __shared__ int pcnt[8];
  __shared__ int g0s;
  int k2 = blockIdx.x, t = threadIdx.x;

  for (int k = t; k < 320; k += 256) wl[k] = Wl[(k / 32) * 96 + 32 * l + (k % 32)];
  if (!dolast)
    for (int k = t; k < 1024; k += 256) w2[k] = Wnext[k];
  if (t < 32) bb[t] = b[t];
  if (t < 80) part[t / 10][t % 10] = 0.f;
  if (t < 8) pcnt[t] = 0;
  if (t == 0) g0s = batch[k2 * 256];

  // row boundaries: per-row degree + LDS scan (rows k2*256 .. k2*256+255)
  int s = bbase[2 * k2];
  int v = (int)rcnt[k2 * 256 + t];
  sA[t] = v;
  __syncthreads();
  int* src = sA;
  int* dst = sB;
  for (int off = 1; off < 256; off <<= 1) {
    int x = src[t];
    if (t >= off) x += src[t - off];
    dst[t] = x;
    __syncthreads();
    int* tm = src; src = dst; dst = tm;
  }
  int p1 = s + src[t];  // start of next row
  int p0 = p1 - v;      // start of this row

  // phase 2: register-accumulated gather
  float acc[32];
#pragma unroll
  for (int j = 0; j < 32; j++) acc[j] = 0.f;
  for (int p = p0; p < p1; p++) {
    int2 pk = cv[p];
    int col = pk.x & 0x7FFFF;
    float vv = __int_as_float(pk.y);
    const float4* zr = (const float4*)(Zin + (size_t)col * 32);
#pragma unroll
    for (int q = 0; q < 8; q++) {
      float4 z = zr[q];
      acc[4 * q + 0] += vv * z.x; acc[4 * q + 1] += vv * z.y;
      acc[4 * q + 2] += vv * z.z; acc[4 * q + 3] += vv * z.w;
    }
  }

  // epilogue: bias, readout, per-graph partials
#pragma unroll
  for (int j = 0; j < 32; j++) acc[j] += bb[j];
  float r[10];
#pragma unroll
  for (int o = 0; o < 10; o++) {
    float a = 0.f;
#pragma unroll
    for (int j = 0; j < 32; j++) a += wl[o * 32 + j] * acc[j];
    r[o] = a;
  }
  int g0 = g0s;
  int g = batch[k2 * 256 + t];
  int gl = g - g0;
  if (gl >= 0 && gl < 8) {
#pragma unroll
    for (int o = 0; o < 10; o++) atomicAdd(&part[gl][o], r[o]);
    if (docnt) atomicAdd(&pcnt[gl], 1);
  } else {
#pragma unroll
    for (int o = 0; o < 10; o++) atomAddF(&S[(size_t)g * 10 + o], r[o]);
    if (docnt) atomAddF(&cnt[g], 1.f);
  }

  // next-layer projection: Zout = leaky(h) @ Wnext^T
  if (!dolast) {
#pragma unroll
    for (int j = 0; j < 32; j++) acc[j] = (acc[j] >= 0.f) ? acc[j] : 0.01f * acc[j];
    float z[32];
#pragma unroll
    for (int o = 0; o < 32; o++) {
      float a = 0.f;
#pragma unroll
      for (int f = 0; f < 32; f++) a += w2[o * 32 + f] * acc[f];
      z[o] = a;
    }
    int row = k2 * 256 + t;
    float4* zr = (float4*)(Zout + (size_t)row * 32);
#pragma unroll
    for (int q = 0; q < 8; q++)
      zr[q] = make_float4(z[4 * q], z[4 * q + 1], z[4 * q + 2], z[4 * q + 3]);
  }

  // flush per-graph partials
  __syncthreads();
  if (t < 80) {
    int gl2 = t / 10, o = t % 10;
    int gg = g0 + gl2;
    float pv = part[gl2][o];
    if (gg < kG && pv != 0.f) atomAddF(&S[(size_t)gg * 10 + o], pv);
  }
  if (docnt && t < 8) {
    int gg = g0 + t;
    if (gg < kG && pcnt[t] > 0) atomAddF(&cnt[gg], (float)pcnt[t]);
  }
}

// out = softmax(concat(S_b / max(cnt_b,1)) @ Wc^T + bc)   Wc: (10,30)
__global__ void kfinal(const float* __restrict__ S, const float* __restrict__ cnt,
                       const float* __restrict__ Wc, const float* __restrict__ bc,
                       float* __restrict__ out) {
  int g = threadIdx.x;  // 512 threads, one per graph
  float o[30];
#pragma unroll
  for (int s = 0; s < 3; s++) {
    float c = cnt[s * kG + g];
    float inv = 1.f / fmaxf(c, 1.f);
#pragma unroll
    for (int j = 0; j < 10; j++)
      o[s * 10 + j] = S[((size_t)s * kG + g) * 10 + j] * inv;
  }
  float z[10];
  float m = -1e30f;
#pragma unroll
  for (int k = 0; k < 10; k++) {
    float t = bc[k];
    for (int j = 0; j < 30; j++) t += Wc[k * 30 + j] * o[j];
    z[k] = t;
    m = fmaxf(m, t);
  }
  float sum = 0.f;
#pragma unroll
  for (int k = 0; k < 10; k++) { z[k] = expf(z[k] - m); sum += z[k]; }
  float r = 1.f / sum;
#pragma unroll
  for (int k = 0; k < 10; k++) out[(size_t)g * 10 + k] = z[k] * r;
}

extern "C" void kernel_launch(void* const* d_in, const int* in_sizes, int n_in,
                              void* d_out, int out_size, void* d_ws, size_t ws_size,
                              hipStream_t stream) {
  const int nb[3] = {262144, 524288, 131072};
  const int eb[3] = {2097152, 4194304, 1048576};

  const int* rowsv[3] = {(const int*)d_in[0], (const int*)d_in[5], (const int*)d_in[10]};
  const int* colsv[3] = {(const int*)d_in[1], (const int*)d_in[6], (const int*)d_in[11]};
  const float* valsv[3] = {(const float*)d_in[2], (const float*)d_in[7], (const float*)d_in[12]};
  const float* Xv[3] = {(const float*)d_in[3], (const float*)d_in[8], (const float*)d_in[13]};
  const int* batchv[3] = {(const int*)d_in[4], (const int*)d_in[9], (const int*)d_in[14]};
  // per-branch weights: W1,b1,W2,b2,W3,b3,Wl,bl at [15..22], [23..30], [31..38]
  const float* W1v[3] = {(const float*)d_in[15], (const float*)d_in[23], (const float*)d_in[31]};
  const float* B1v[3] = {(const float*)d_in[16], (const float*)d_in[24], (const float*)d_in[32]};
  const float* W2v[3] = {(const float*)d_in[17], (const float*)d_in[25], (const float*)d_in[33]};
  const float* B2v[3] = {(const float*)d_in[18], (const float*)d_in[26], (const float*)d_in[34]};
  const float* W3v[3] = {(const float*)d_in[19], (const float*)d_in[27], (const float*)d_in[35]};
  const float* B3v[3] = {(const float*)d_in[20], (const float*)d_in[28], (const float*)d_in[36]};
  const float* Wlv[3] = {(const float*)d_in[21], (const float*)d_in[29], (const float*)d_in[37]};
  const float* Wc = (const float*)d_in[39];
  const float* bc = (const float*)d_in[40];

  char* ws = (char*)d_ws;
  int* tot = (int*)(ws + OFF_TOT);
  int* bbase = (int*)(ws + OFF_BB);
  int2* cv = (int2*)(ws + OFF_CV);
  float* Z = (float*)(ws + OFF_Z);
  float* ZB = (float*)(ws + OFF_ZB);
  float* S = (float*)(ws + OFF_S);
  float* cnt = (float*)(ws + OFF_CNT);
  unsigned char* rcnt = (unsigned char*)(ws + OFF_RC);
  float* out = (float*)d_out;

  hipMemsetAsync(S, 0, (size_t)3 * kG * 10 * 4 + (size_t)3 * kG * 4, stream);

  for (int b = 0; b < 3; b++) {
    const int n = nb[b], e = eb[b];
    const int NB = n / 128;       // radix buckets (<=4096)
    const int chunk = e / kNCH;   // edges per partition block
    const float* Bl[3] = {B1v[b], B2v[b], B3v[b]};
    float* Sb = S + (size_t)b * kG * 10;
    float* cb = cnt + (size_t)b * kG;
    int* cnts = (int*)(ws + OFF_Z);   // Z region idle during build (4MB)
    int2* tmp = (int2*)(ws + OFF_ZB); // ZB region idle during build (32MB)

    // deterministic partition into self-contained, row-sorted cv stream
    kphist<<<kNCH, 256, 0, stream>>>(rowsv[b], cnts, NB, chunk);
    kpscan1<<<NB, 256, 0, stream>>>(cnts, tot, NB);
    kbscan<<<1, 1024, 0, stream>>>(tot, bbase, NB, e);
    kpscatter<<<kNCH, 256, 0, stream>>>(rowsv[b], colsv[b], valsv[b], cnts,
                                        bbase, tmp, NB, chunk);
    kplace<<<NB, 256, 0, stream>>>(tmp, bbase, cv, rcnt);

    // layer 1 projection (overwrites cnts overlay; build is complete)
    kproj<<<n / 256, 256, 0, stream>>>(Xv[b], W1v[b], Z);

    // 3 fused layers: Z -> ZB -> Z -> (readout only)
    kfused<<<NB / 2, 256, 0, stream>>>(cv, bbase, rcnt, Z, ZB, Bl[0], Wlv[b], 0,
                                       W2v[b], batchv[b], Sb, cb, 1, 0);
    kfused<<<NB / 2, 256, 0, stream>>>(cv, bbase, rcnt, ZB, Z, Bl[1], Wlv[b], 1,
                                       W3v[b], batchv[b], Sb, cb, 0, 0);
    kfused<<<NB / 2, 256, 0, stream>>>(cv, bbase, rcnt, Z, nullptr, Bl[2], Wlv[b], 2,
                                       W2v[b] /*unused*/, batchv[b], Sb, cb, 0, 1);
  }

  kfinal<<<1, 512, 0, stream>>>(S, cnt, Wc, bc, out);
}